// Round 20
// baseline (735.159 us; speedup 1.0000x reference)
//
#include <hip/hip_runtime.h>

// MultiHeadGraphAttention: B=8, N=1024, IN=OUT=256, H=8, d_k=32
// All-fp16 pipeline. Bias precompute FUSED into k_attn as a producer-consumer
// pipeline: per batch, blocks j=0..15 each produce one 64-col bias slab
// (staggered across loop iterations), released via agent-scope atomic flags;
// consumers acquire the flag per tile. Bounded-spin fallback recomputes the
// fragment from raw A/D (bit-identical) -> deadlock-proof, deterministic.
//   k1: X f32->f16 + W transpose->f16
//   k2: QKV GEMM (W-stationary, f16 MFMA, Q pre-scaled)
//   k3: fused attention + bias production (K/V LDS-resident, XOR-swizzled)
//   k4: output projection

typedef _Float16 f16x8 __attribute__((ext_vector_type(8)));
typedef __fp16 h16x2 __attribute__((ext_vector_type(2)));   // cvt_pkrtz result type
typedef float f32x4 __attribute__((ext_vector_type(4)));
typedef int i32x4 __attribute__((ext_vector_type(4)));
typedef unsigned short u16x8 __attribute__((ext_vector_type(8)));

#define DEV static __device__ __forceinline__

#define LOG2E 1.4426950408889634f
#define QSCALE 0.2550351062f   // (1/sqrt(32)) * log2(e)

DEV unsigned short f2h(float f) {    // f32 -> fp16 bits (RNE)
  _Float16 h = (_Float16)f;
  unsigned short u;
  __builtin_memcpy(&u, &h, 2);
  return u;
}

DEV f32x4 mfma16h(f16x8 a, f16x8 b, f32x4 c) {
  return __builtin_amdgcn_mfma_f32_16x16x32_f16(a, b, c, 0, 0, 0);
}

DEV f16x8 ldfragh(const unsigned short* p) {
  return *reinterpret_cast<const f16x8*>(p);
}

// ---------------- k1: X f32 -> f16 ; W -> f16 transposed [n][k] ----------------
__global__ __launch_bounds__(256) void k_prep_xw(
    const float* __restrict__ X,
    const float* __restrict__ Wq, const float* __restrict__ Wk,
    const float* __restrict__ Wv, const float* __restrict__ Wo,
    unsigned short* __restrict__ Xh, unsigned short* __restrict__ Wt) {
  const int tid = blockIdx.x * 256 + threadIdx.x;
  const int NX4 = (8192 * 256) / 4;           // 524,288 X quads
  if (tid < NX4) {
    float4 v = reinterpret_cast<const float4*>(X)[tid];
    union { h16x2 h2[2]; ushort4 u; } o;
    o.h2[0] = __builtin_amdgcn_cvt_pkrtz(v.x, v.y);
    o.h2[1] = __builtin_amdgcn_cvt_pkrtz(v.z, v.w);
    reinterpret_cast<ushort4*>(Xh)[tid] = o.u;
  } else {
    int t = tid - NX4;                        // 0 .. 262143
    int mat = t >> 16;
    int e = t & 65535;
    int n = e >> 8, k = e & 255;              // output Wt[mat][n][k]
    const float* W = (mat == 0) ? Wq : (mat == 1) ? Wk : (mat == 2) ? Wv : Wo;
    Wt[t] = f2h(W[k * 256 + n]);
  }
}

// ---------------- k2: QKV projection GEMM (W-stationary, f16) ------------------
// grid 384: bx&31 = 256-row m-chunk (16 m-tiles), bx>>5 = mat*4 + col-slab.
__global__ __launch_bounds__(256, 2) void k_qkv(
    const unsigned short* __restrict__ Xh, const unsigned short* __restrict__ Wt,
    const float* __restrict__ bq, const float* __restrict__ bk,
    const float* __restrict__ bv,
    unsigned short* __restrict__ Qb, unsigned short* __restrict__ Kb,
    unsigned short* __restrict__ Vt) {
  const int lane = threadIdx.x & 63;
  const int w = threadIdx.x >> 6;
  const int lr = lane & 15, lg = lane >> 4;
  const int yy = blockIdx.x >> 5;             // 0..11 = mat*4 + col-slab
  const int mat = yy >> 2;
  const int nloc = (yy & 3) * 64 + w * 16;
  const int mbase = (blockIdx.x & 31) << 8;

  const unsigned short* Wm = Wt + mat * 65536;
  const float* bias = (mat == 0) ? bq : (mat == 1) ? bk : bv;

  f16x8 bfr[8];
  #pragma unroll
  for (int ks = 0; ks < 8; ++ks)
    bfr[ks] = ldfragh(Wm + (nloc + lr) * 256 + ks * 32 + lg * 8);
  const float bb = bias[nloc + lr];
  const int cm = nloc + lr;
  const int hh = cm >> 5, d = cm & 31;

  for (int mt = 0; mt < 16; ++mt) {
    const int m0 = mbase + mt * 16;
    f16x8 a[8];
    #pragma unroll
    for (int ks = 0; ks < 8; ++ks)
      a[ks] = ldfragh(Xh + (m0 + lr) * 256 + ks * 32 + lg * 8);
    f32x4 acc = {0.f, 0.f, 0.f, 0.f};
    #pragma unroll
    for (int ks = 0; ks < 8; ++ks)
      acc = mfma16h(a[ks], bfr[ks], acc);

    if (mat == 2) {                           // V transposed: 4 consecutive halfs
      union { h16x2 h2[2]; ushort4 u; } vv;
      vv.h2[0] = __builtin_amdgcn_cvt_pkrtz(acc[0] + bb, acc[1] + bb);
      vv.h2[1] = __builtin_amdgcn_cvt_pkrtz(acc[2] + bb, acc[3] + bb);
      const int row = m0 + lg * 4;
      const int bidx = row >> 10, nn = row & 1023;
      *reinterpret_cast<ushort4*>(&Vt[(((bidx * 8 + hh) * 32) + d) * 1024 + nn]) = vv.u;
    } else if (mat == 0) {
      #pragma unroll
      for (int i = 0; i < 4; ++i) {
        const int row = m0 + lg * 4 + i;
        const int bidx = row >> 10, nn = row & 1023;
        Qb[(((bidx * 8 + hh) * 1024) + nn) * 32 + d] = f2h((acc[i] + bb) * QSCALE);
      }
    } else {
      #pragma unroll
      for (int i = 0; i < 4; ++i) {
        const int row = m0 + lg * 4 + i;
        const int bidx = row >> 10, nn = row & 1023;
        Kb[(((bidx * 8 + hh) * 1024) + nn) * 32 + d] = f2h(acc[i] + bb);
      }
    }
  }
}

// produce one 64-col bias slab (cols [slab*64, +64), all 1024 rows of batch b)
// with all 512 threads; release flag when done.
DEV void produce_slab(const int* __restrict__ A, const float* __restrict__ D,
                      unsigned short* __restrict__ Bias, int* __restrict__ Flags,
                      int b, int slab, float c, int tid) {
  const size_t rowbase = ((size_t)b << 20) + slab * 64 + (tid & 15) * 4;
  const int r0 = tid >> 4;                    // 0..31
  #pragma unroll 4
  for (int pass = 0; pass < 32; ++pass) {
    const size_t off = rowbase + (size_t)(pass * 32 + r0) * 1024;
    const i32x4 a = *reinterpret_cast<const i32x4*>(A + off);
    const f32x4 d = *reinterpret_cast<const f32x4*>(D + off);
    ushort4 o;
    unsigned short* op = (unsigned short*)&o;
    #pragma unroll
    for (int i = 0; i < 4; ++i)
      op[i] = f2h(a[i] <= 0 ? -60000.0f : c * d[i]);
    *reinterpret_cast<ushort4*>(Bias + off) = o;
  }
  __syncthreads();
  __threadfence();
  if (tid == 0)
    __hip_atomic_store(&Flags[b * 16 + slab], 1, __ATOMIC_RELEASE,
                       __HIP_MEMORY_SCOPE_AGENT);
}

// ---------------- k3: fused attention + bias production ------------------------
// grid 256 = (b,h,qq), bi = (h*4+qq)*8 + b (XCD-affine), 1 block/CU (all
// co-resident). j = h*4+qq; blocks j<16 produce bias slab j for batch b,
// staggered: j<2 pre-loop, else at iteration j-2. Consumers acquire flag[b][t]
// per tile; bounded-spin fallback recomputes the fragment from raw A/D with
// bit-identical math (deadlock-proof). Attn core identical to the proven R16.
__global__ __launch_bounds__(512, 2) void k_attn(
    const unsigned short* __restrict__ Qb, const unsigned short* __restrict__ Kb,
    const unsigned short* __restrict__ Vt, const int* __restrict__ A,
    const float* __restrict__ D, const float* __restrict__ dsc,
    unsigned short* __restrict__ Bias, int* __restrict__ Flags,
    unsigned short* __restrict__ AO) {
  __shared__ alignas(16) unsigned short Klds[1024 * 32];    // 64KB, seg^=row&3
  __shared__ alignas(16) unsigned short Vlds[32 * 1024];    // 64KB, chunk^=row&7
  __shared__ alignas(16) unsigned short Sbuf[8][2][16][40]; // 20KB: 32 keys + pad

  const int tid = threadIdx.x;
  const int lane = tid & 63;
  const int w = tid >> 6;
  const int lr = lane & 15, lg = lane >> 4;
  const int bi = blockIdx.x;
  const int b = bi & 7;                       // XCD affinity
  const int j = bi >> 3;                      // 0..31 = h*4+qq
  const int h = j >> 2, qq = j & 3;
  const int q0w = qq * 256 + w * 32;
  const float c = -dsc[0] * LOG2E;

  const unsigned short* Kg = Kb + ((size_t)(b * 8 + h) << 15);
  const unsigned short* Vg = Vt + ((size_t)(b * 8 + h) << 15);
  const unsigned short* Qh = Qb + ((size_t)(b * 8 + h) << 15);

  // ---- stage K: linear global 16B/thread -> swizzled LDS ----
  #pragma unroll
  for (int p = 0; p < 8; ++p) {
    const int cc = tid + p * 512;             // 16B chunk id, 4096 total
    const int row = cc >> 2, seg = cc & 3;
    const u16x8 v = *reinterpret_cast<const u16x8*>(Kg + cc * 8);
    *reinterpret_cast<u16x8*>(&Klds[row * 32 + ((seg ^ (row & 3)) << 3)]) = v;
  }
  // ---- stage V^T: linear global -> swizzled LDS ----
  #pragma unroll
  for (int p = 0; p < 8; ++p) {
    const int cc = tid + p * 512;             // 16B chunk id, 4096 total
    const int row = cc >> 7, ch = cc & 127;
    const u16x8 v = *reinterpret_cast<const u16x8*>(Vg + cc * 8);
    *reinterpret_cast<u16x8*>(&Vlds[row * 1024 + ((ch ^ (row & 7)) << 3)]) = v;
  }

  // early production of slabs 0,1 (needed at t=0,1)
  if (j < 2) produce_slab(A, D, Bias, Flags, b, j, c, tid);

  // Q fragments for the wave's 2 subtiles; bias row pointers
  f16x8 qf[2];
  qf[0] = ldfragh(Qh + (q0w + lr) * 32 + lg * 8);
  qf[1] = ldfragh(Qh + (q0w + 16 + lr) * 32 + lg * 8);
  const unsigned short* Br0 = Bias + ((size_t)b << 20) + (size_t)(q0w + lr) * 1024;
  const unsigned short* Br1 = Br0 + (size_t)16 * 1024;

  __syncthreads();

  f32x4 o[2][2];                              // [sub][dh]
  f32x4 lacc[2];                              // [sub] l accumulator (ones-MFMA)
  #pragma unroll
  for (int s = 0; s < 2; ++s) {
    #pragma unroll
    for (int dh = 0; dh < 2; ++dh) o[s][dh] = f32x4{0.f, 0.f, 0.f, 0.f};
    lacc[s] = f32x4{0.f, 0.f, 0.f, 0.f};
  }
  f16x8 onesv;
  #pragma unroll
  for (int i = 0; i < 8; ++i) onesv[i] = (_Float16)1.0f;

  for (int t = 0; t < 16; ++t) {
    const int k0 = t << 6;

    // staggered production: block j produces slab j at iteration j-2
    if (j >= 2 && j < 16 && t == j - 2)
      produce_slab(A, D, Bias, Flags, b, j, c, tid);

    // acquire this tile's bias slab (bounded spin -> fallback)
    bool fb = false;
    {
      int spins = 0;
      while (__hip_atomic_load(&Flags[b * 16 + t], __ATOMIC_ACQUIRE,
                               __HIP_MEMORY_SCOPE_AGENT) == 0) {
        __builtin_amdgcn_s_sleep(2);
        if (++spins > 5000) { fb = true; break; }
      }
    }

    // bias fragments [sub][half]
    u16x8 bc[2][2];
    if (!fb) {
      #pragma unroll
      for (int hf = 0; hf < 2; ++hf) {
        bc[0][hf] = *reinterpret_cast<const u16x8*>(Br0 + k0 + hf * 32 + lg * 8);
        bc[1][hf] = *reinterpret_cast<const u16x8*>(Br1 + k0 + hf * 32 + lg * 8);
      }
    } else {
      // fallback: recompute from raw A/D, bit-identical to produce_slab
      #pragma unroll
      for (int s = 0; s < 2; ++s)
        #pragma unroll
        for (int hf = 0; hf < 2; ++hf) {
          const size_t base = ((size_t)b << 20) +
              (size_t)(q0w + s * 16 + lr) * 1024 + k0 + hf * 32 + lg * 8;
          const i32x4 a0 = *reinterpret_cast<const i32x4*>(A + base);
          const i32x4 a1 = *reinterpret_cast<const i32x4*>(A + base + 4);
          const f32x4 d0 = *reinterpret_cast<const f32x4*>(D + base);
          const f32x4 d1 = *reinterpret_cast<const f32x4*>(D + base + 4);
          union { ushort4 q[2]; u16x8 v; } bb;
          unsigned short* bp = (unsigned short*)&bb;
          #pragma unroll
          for (int i = 0; i < 4; ++i) {
            bp[i]     = f2h(a0[i] <= 0 ? -60000.0f : c * d0[i]);
            bp[i + 4] = f2h(a1[i] <= 0 ? -60000.0f : c * d1[i]);
          }
          bc[s][hf] = bb.v;
        }
    }

    // K fragments from LDS (seg XOR swizzle)
    f16x8 kf[4];
    #pragma unroll
    for (int st = 0; st < 4; ++st) {
      const int row = k0 + st * 16 + lr;
      kf[st] = *reinterpret_cast<const f16x8*>(
          &Klds[row * 32 + ((lg ^ (lr & 3)) << 3)]);
    }
    // V^T fragments from LDS (chunk XOR swizzle); shared by both subtiles
    f16x8 vf[2][2];
    #pragma unroll
    for (int dh = 0; dh < 2; ++dh)
      #pragma unroll
      for (int hf = 0; hf < 2; ++hf) {
        const int row = dh * 16 + lr;
        const int ch = t * 8 + ((hf * 4 + lg) ^ (lr & 7));
        vf[dh][hf] = *reinterpret_cast<const f16x8*>(&Vlds[row * 1024 + ch * 8]);
      }

    // ---- two 32-key halves; each half interleaves BOTH subtiles ----
    #pragma unroll
    for (int hf = 0; hf < 2; ++hf) {
      const f32x4 zz = {0.f, 0.f, 0.f, 0.f};
      f32x4 sv[2][2];
      #pragma unroll
      for (int s = 0; s < 2; ++s)
        #pragma unroll
        for (int st = 0; st < 2; ++st)
          sv[s][st] = mfma16h(kf[hf * 2 + st], qf[s], zz);

      #pragma unroll
      for (int s = 0; s < 2; ++s)
        #pragma unroll
        for (int st = 0; st < 2; ++st) {
          union { h16x2 h2[2]; ushort4 u; } sw;
          sw.h2[0] = __builtin_amdgcn_cvt_pkrtz(sv[s][st][0], sv[s][st][1]);
          sw.h2[1] = __builtin_amdgcn_cvt_pkrtz(sv[s][st][2], sv[s][st][3]);
          *reinterpret_cast<ushort4*>(&Sbuf[w][s][lr][st * 16 + lg * 4]) = sw.u;
        }

      #pragma unroll
      for (int s = 0; s < 2; ++s) {
        const f16x8 sf = *reinterpret_cast<const f16x8*>(&Sbuf[w][s][lr][lg * 8]);
        const f16x8 bfv = *reinterpret_cast<const f16x8*>(&bc[s][hf]);
        const f16x8 sb = sf + bfv;            // v_pk_add_f16
        float e[8];
        #pragma unroll
        for (int i = 0; i < 8; ++i) e[i] = exp2f((float)sb[i]);
        union { h16x2 h2[4]; f16x8 v; } pfu;
        #pragma unroll
        for (int i = 0; i < 4; ++i)
          pfu.h2[i] = __builtin_amdgcn_cvt_pkrtz(e[2 * i], e[2 * i + 1]);
        const f16x8 pf = pfu.v;
        o[s][0] = mfma16h(vf[0][hf], pf, o[s][0]);
        o[s][1] = mfma16h(vf[1][hf], pf, o[s][1]);
        lacc[s] = mfma16h(onesv, pf, lacc[s]);  // l += sum_k p (all rows equal)
      }
    }
  }

  // epilogue: l = lacc[s][0] exactly (B-operand reduction spans all lanes)
  #pragma unroll
  for (int s = 0; s < 2; ++s) {
    const float linv = 1.0f / lacc[s][0];
    ushort4 r0, r1;
    unsigned short* r0p = (unsigned short*)&r0;
    unsigned short* r1p = (unsigned short*)&r1;
    #pragma unroll
    for (int i = 0; i < 4; ++i) {
      r0p[i] = f2h(o[s][0][i] * linv);
      r1p[i] = f2h(o[s][1][i] * linv);
    }
    const int row = (b << 10) + q0w + s * 16 + lr;
    *reinterpret_cast<ushort4*>(&AO[row * 256 + h * 32 + lg * 4]) = r0;
    *reinterpret_cast<ushort4*>(&AO[row * 256 + h * 32 + 16 + lg * 4]) = r1;
  }
}

// ---------------- k4: output projection (W-stationary, f16) --------------------
__global__ __launch_bounds__(256, 2) void k_oproj(
    const unsigned short* __restrict__ AO, const unsigned short* __restrict__ Wto,
    const float* __restrict__ bo, float* __restrict__ out) {
  const int lane = threadIdx.x & 63;
  const int w = threadIdx.x >> 6;
  const int lr = lane & 15, lg = lane >> 4;
  const int c0 = blockIdx.y * 64 + w * 16;
  const int mbase = blockIdx.x << 7;

  f16x8 bfr[8];
  #pragma unroll
  for (int ks = 0; ks < 8; ++ks)
    bfr[ks] = ldfragh(Wto + (c0 + lr) * 256 + ks * 32 + lg * 8);
  const float bb = bo[c0 + lr];

  for (int mt = 0; mt < 8; ++mt) {
    const int m0 = mbase + mt * 16;
    f16x8 a[8];
    #pragma unroll
    for (int ks = 0; ks < 8; ++ks)
      a[ks] = ldfragh(AO + (m0 + lr) * 256 + ks * 32 + lg * 8);
    f32x4 acc = {0.f, 0.f, 0.f, 0.f};
    #pragma unroll
    for (int ks = 0; ks < 8; ++ks)
      acc = mfma16h(a[ks], bfr[ks], acc);
    #pragma unroll
    for (int i = 0; i < 4; ++i) {
      const int row = m0 + lg * 4 + i;
      out[row * 256 + c0 + lr] = acc[i] + bb;
    }
  }
}

extern "C" void kernel_launch(void* const* d_in, const int* in_sizes, int n_in,
                              void* d_out, int out_size, void* d_ws, size_t ws_size,
                              hipStream_t stream) {
  const float* X   = (const float*)d_in[0];
  const int*   A   = (const int*)d_in[1];
  const float* D   = (const float*)d_in[2];
  const float* Wq  = (const float*)d_in[3];
  const float* bq  = (const float*)d_in[4];
  const float* Wk  = (const float*)d_in[5];
  const float* bk  = (const float*)d_in[6];
  const float* Wv  = (const float*)d_in[7];
  const float* bv  = (const float*)d_in[8];
  const float* Wo  = (const float*)d_in[9];
  const float* bo  = (const float*)d_in[10];
  const float* dsc = (const float*)d_in[11];
  float* out = (float*)d_out;

  unsigned short* ws = (unsigned short*)d_ws;
  unsigned short* Xh   = ws;                   // 2,097,152  (reused as AO later)
  unsigned short* Wt   = ws + 2097152;         //   262,144
  unsigned short* Qb   = ws + 2359296;         // 2,097,152
  unsigned short* Kb   = ws + 4456448;         // 2,097,152
  unsigned short* Vt   = ws + 6553600;         // 2,097,152
  unsigned short* Bias = ws + 8650752;         // 8,388,608
  int* Flags           = (int*)(ws + 17039360); // 128 ints
  unsigned short* AO   = Xh;                   // alias: Xh dead after k_qkv

  hipLaunchKernelGGL(k_prep_xw, dim3(3072), dim3(256), 0, stream,
                     X, Wq, Wk, Wv, Wo, Xh, Wt);
  hipLaunchKernelGGL(k_qkv, dim3(384), dim3(256), 0, stream,
                     Xh, Wt, bq, bk, bv, Qb, Kb, Vt);
  hipMemsetAsync(Flags, 0, 128 * sizeof(int), stream);
  hipLaunchKernelGGL(k_attn, dim3(256), dim3(512), 0, stream,
                     Qb, Kb, Vt, A, D, dsc, Bias, Flags, AO);
  hipLaunchKernelGGL(k_oproj, dim3(64, 4), dim3(256), 0, stream,
                     AO, Wt + 196608, bo, out);
}

// Round 22
// 86.991 us; speedup vs baseline: 8.4509x; 8.4509x over previous
//
#include <hip/hip_runtime.h>

// MultiHeadGraphAttention: B=8, N=1024, IN=OUT=256, H=8, d_k=32
// All-fp16 pipeline, stage-overlapped (R16 structure):
//   k1: X f32->f16 + W transpose->f16
//   k2: QKV GEMM blocks (0..383) + bias-precompute blocks (384..8575) fused;
//       bias stream uses NONTEMPORAL loads/stores (bypass L2/L3 allocation)
//   k3: fused masked attention (K/V LDS-resident, XOR-swizzled, S^T via LDS,
//       packed-f16 bias add, fixed-max exp2 softmax, l via ones-MFMA)
//   k4: output projection (W-stationary)

typedef _Float16 f16x8 __attribute__((ext_vector_type(8)));
typedef __fp16 h16x2 __attribute__((ext_vector_type(2)));   // cvt_pkrtz result type
typedef float f32x4 __attribute__((ext_vector_type(4)));
typedef int i32x4 __attribute__((ext_vector_type(4)));
typedef unsigned short u16x8 __attribute__((ext_vector_type(8)));
typedef unsigned short u16x4 __attribute__((ext_vector_type(4)));

#define DEV static __device__ __forceinline__

#define LOG2E 1.4426950408889634f
#define QSCALE 0.2550351062f   // (1/sqrt(32)) * log2(e)

DEV unsigned short f2h(float f) {    // f32 -> fp16 bits (RNE)
  _Float16 h = (_Float16)f;
  unsigned short u;
  __builtin_memcpy(&u, &h, 2);
  return u;
}

DEV f32x4 mfma16h(f16x8 a, f16x8 b, f32x4 c) {
  return __builtin_amdgcn_mfma_f32_16x16x32_f16(a, b, c, 0, 0, 0);
}

DEV f16x8 ldfragh(const unsigned short* p) {
  return *reinterpret_cast<const f16x8*>(p);
}

// ---------------- k1: X f32 -> f16 ; W -> f16 transposed [n][k] ----------------
// grid 3072: 2048 X-quad blocks + 1024 W blocks.
__global__ __launch_bounds__(256) void k_prep_xw(
    const float* __restrict__ X,
    const float* __restrict__ Wq, const float* __restrict__ Wk,
    const float* __restrict__ Wv, const float* __restrict__ Wo,
    unsigned short* __restrict__ Xh, unsigned short* __restrict__ Wt) {
  const int tid = blockIdx.x * 256 + threadIdx.x;
  const int NX4 = (8192 * 256) / 4;           // 524,288 X quads
  if (tid < NX4) {
    float4 v = reinterpret_cast<const float4*>(X)[tid];
    union { h16x2 h2[2]; ushort4 u; } o;
    o.h2[0] = __builtin_amdgcn_cvt_pkrtz(v.x, v.y);
    o.h2[1] = __builtin_amdgcn_cvt_pkrtz(v.z, v.w);
    reinterpret_cast<ushort4*>(Xh)[tid] = o.u;
  } else {
    int t = tid - NX4;                        // 0 .. 262143
    int mat = t >> 16;
    int e = t & 65535;
    int n = e >> 8, k = e & 255;              // output Wt[mat][n][k]
    const float* W = (mat == 0) ? Wq : (mat == 1) ? Wk : (mat == 2) ? Wv : Wo;
    Wt[t] = f2h(W[k * 256 + n]);
  }
}

// ---------------- k2: QKV GEMM + bias precompute (nontemporal), fused ----------
// blocks 0..383: W-stationary GEMM (bx&31 = 256-row m-chunk, bx>>5 = mat*4+slab)
// blocks 384..8575: Bias[q4] fp16 = A<=0 ? -60000 : -ds*log2e*D, 1 quad/thread,
//   nontemporal loads/stores (once-touched stream; bypass cache allocation).
__global__ __launch_bounds__(256) void k_qkv_bias(
    const unsigned short* __restrict__ Xh, const unsigned short* __restrict__ Wt,
    const float* __restrict__ bq, const float* __restrict__ bk,
    const float* __restrict__ bv,
    const int* __restrict__ A, const float* __restrict__ D,
    const float* __restrict__ dscale,
    unsigned short* __restrict__ Qb, unsigned short* __restrict__ Kb,
    unsigned short* __restrict__ Vt, unsigned short* __restrict__ Bias) {
  if (blockIdx.x >= 384) {
    // ---- bias stream (nontemporal) ----
    const int t = (blockIdx.x - 384) * 256 + threadIdx.x;   // quad id, < 2,097,152
    const i32x4 a4 = __builtin_nontemporal_load(reinterpret_cast<const i32x4*>(A) + t);
    const f32x4 d4 = __builtin_nontemporal_load(reinterpret_cast<const f32x4*>(D) + t);
    const float c = -dscale[0] * LOG2E;
    u16x4 o;
    #pragma unroll
    for (int i = 0; i < 4; ++i)
      o[i] = f2h(a4[i] <= 0 ? -60000.0f : c * d4[i]);
    __builtin_nontemporal_store(o, reinterpret_cast<u16x4*>(Bias) + t);
    return;
  }

  // ---- QKV GEMM (W-stationary) ----
  const int lane = threadIdx.x & 63;
  const int w = threadIdx.x >> 6;
  const int lr = lane & 15, lg = lane >> 4;
  const int yy = blockIdx.x >> 5;             // 0..11 = mat*4 + col-slab
  const int mat = yy >> 2;
  const int nloc = (yy & 3) * 64 + w * 16;
  const int mbase = (blockIdx.x & 31) << 8;

  const unsigned short* Wm = Wt + mat * 65536;
  const float* bias = (mat == 0) ? bq : (mat == 1) ? bk : bv;

  f16x8 bfr[8];
  #pragma unroll
  for (int ks = 0; ks < 8; ++ks)
    bfr[ks] = ldfragh(Wm + (nloc + lr) * 256 + ks * 32 + lg * 8);
  const float bb = bias[nloc + lr];
  const int cm = nloc + lr;
  const int hh = cm >> 5, d = cm & 31;

  for (int mt = 0; mt < 16; ++mt) {
    const int m0 = mbase + mt * 16;
    f16x8 a[8];
    #pragma unroll
    for (int ks = 0; ks < 8; ++ks)
      a[ks] = ldfragh(Xh + (m0 + lr) * 256 + ks * 32 + lg * 8);
    f32x4 acc = {0.f, 0.f, 0.f, 0.f};
    #pragma unroll
    for (int ks = 0; ks < 8; ++ks)
      acc = mfma16h(a[ks], bfr[ks], acc);

    if (mat == 2) {                           // V transposed: 4 consecutive halfs
      union { h16x2 h2[2]; ushort4 u; } vv;
      vv.h2[0] = __builtin_amdgcn_cvt_pkrtz(acc[0] + bb, acc[1] + bb);
      vv.h2[1] = __builtin_amdgcn_cvt_pkrtz(acc[2] + bb, acc[3] + bb);
      const int row = m0 + lg * 4;
      const int bidx = row >> 10, nn = row & 1023;
      *reinterpret_cast<ushort4*>(&Vt[(((bidx * 8 + hh) * 32) + d) * 1024 + nn]) = vv.u;
    } else if (mat == 0) {
      #pragma unroll
      for (int i = 0; i < 4; ++i) {
        const int row = m0 + lg * 4 + i;
        const int bidx = row >> 10, nn = row & 1023;
        Qb[(((bidx * 8 + hh) * 1024) + nn) * 32 + d] = f2h((acc[i] + bb) * QSCALE);
      }
    } else {
      #pragma unroll
      for (int i = 0; i < 4; ++i) {
        const int row = m0 + lg * 4 + i;
        const int bidx = row >> 10, nn = row & 1023;
        Kb[(((bidx * 8 + hh) * 1024) + nn) * 32 + d] = f2h(acc[i] + bb);
      }
    }
  }
}

// ---------------- k3: fused masked attention (all-f16) -------------------------
// grid 256 = (b,h,q-quarter), bi = (h*4+qq)*8 + b  (XCD-affine). 1 block/CU.
// block 512 = 8 waves; wave w owns 32 q-rows (2 subtiles of 16).
// K (64KB) + V^T (64KB) staged in LDS once, XOR-swizzled. Each 64-key tile is
// processed as two 32-key halves; per half, BOTH subtiles' S^T are written to
// disjoint Sbuf regions before either is read. Bias added packed-f16 in
// B-fragment layout; p = exp2(s+bias) (fixed max 0, masked -> exact 0);
// l via ones-MFMA.
__global__ __launch_bounds__(512, 2) void k_attn(
    const unsigned short* __restrict__ Qb, const unsigned short* __restrict__ Kb,
    const unsigned short* __restrict__ Vt, const unsigned short* __restrict__ Bias,
    unsigned short* __restrict__ AO) {
  __shared__ alignas(16) unsigned short Klds[1024 * 32];    // 64KB, seg^=row&3
  __shared__ alignas(16) unsigned short Vlds[32 * 1024];    // 64KB, chunk^=row&7
  __shared__ alignas(16) unsigned short Sbuf[8][2][16][40]; // 20KB: 32 keys + pad

  const int tid = threadIdx.x;
  const int lane = tid & 63;
  const int w = tid >> 6;
  const int lr = lane & 15, lg = lane >> 4;
  const int bi = blockIdx.x;
  const int b = bi & 7;                       // XCD affinity
  const int j = bi >> 3;
  const int h = j >> 2, qq = j & 3;
  const int q0w = qq * 256 + w * 32;

  const unsigned short* Kg = Kb + ((size_t)(b * 8 + h) << 15);
  const unsigned short* Vg = Vt + ((size_t)(b * 8 + h) << 15);
  const unsigned short* Qh = Qb + ((size_t)(b * 8 + h) << 15);

  // ---- stage K: linear global 16B/thread -> swizzled LDS ----
  #pragma unroll
  for (int p = 0; p < 8; ++p) {
    const int c = tid + p * 512;              // 16B chunk id, 4096 total
    const int row = c >> 2, seg = c & 3;
    const u16x8 v = *reinterpret_cast<const u16x8*>(Kg + c * 8);
    *reinterpret_cast<u16x8*>(&Klds[row * 32 + ((seg ^ (row & 3)) << 3)]) = v;
  }
  // ---- stage V^T: linear global -> swizzled LDS ----
  #pragma unroll
  for (int p = 0; p < 8; ++p) {
    const int c = tid + p * 512;              // 16B chunk id, 4096 total
    const int row = c >> 7, ch = c & 127;
    const u16x8 v = *reinterpret_cast<const u16x8*>(Vg + c * 8);
    *reinterpret_cast<u16x8*>(&Vlds[row * 1024 + ((ch ^ (row & 7)) << 3)]) = v;
  }

  // Q fragments for the wave's 2 subtiles, bias base pointers
  f16x8 qf[2];
  qf[0] = ldfragh(Qh + (q0w + lr) * 32 + lg * 8);
  qf[1] = ldfragh(Qh + (q0w + 16 + lr) * 32 + lg * 8);
  const unsigned short* Br0 = Bias + ((size_t)b << 20) + (size_t)(q0w + lr) * 1024;
  const unsigned short* Br1 = Br0 + (size_t)16 * 1024;

  // bias prefetch for tile 0: [sub][half], half = 32 keys
  u16x8 bc[2][2], bn[2][2];
  #pragma unroll
  for (int hf = 0; hf < 2; ++hf) {
    bc[0][hf] = *reinterpret_cast<const u16x8*>(Br0 + hf * 32 + lg * 8);
    bc[1][hf] = *reinterpret_cast<const u16x8*>(Br1 + hf * 32 + lg * 8);
  }

  __syncthreads();

  f32x4 o[2][2];                              // [sub][dh]
  f32x4 lacc[2];                              // [sub] l accumulator (ones-MFMA)
  #pragma unroll
  for (int s = 0; s < 2; ++s) {
    #pragma unroll
    for (int dh = 0; dh < 2; ++dh) o[s][dh] = f32x4{0.f, 0.f, 0.f, 0.f};
    lacc[s] = f32x4{0.f, 0.f, 0.f, 0.f};
  }
  f16x8 onesv;
  #pragma unroll
  for (int i = 0; i < 8; ++i) onesv[i] = (_Float16)1.0f;

  for (int t = 0; t < 16; ++t) {
    const int k0 = t << 6;
    if (t < 15) {                             // bias(t+1) prefetch (HBM stream)
      #pragma unroll
      for (int hf = 0; hf < 2; ++hf) {
        bn[0][hf] = *reinterpret_cast<const u16x8*>(Br0 + k0 + 64 + hf * 32 + lg * 8);
        bn[1][hf] = *reinterpret_cast<const u16x8*>(Br1 + k0 + 64 + hf * 32 + lg * 8);
      }
    }

    // K fragments from LDS (seg XOR swizzle)
    f16x8 kf[4];
    #pragma unroll
    for (int st = 0; st < 4; ++st) {
      const int row = k0 + st * 16 + lr;
      kf[st] = *reinterpret_cast<const f16x8*>(
          &Klds[row * 32 + ((lg ^ (lr & 3)) << 3)]);
    }
    // V^T fragments from LDS (chunk XOR swizzle); shared by both subtiles
    f16x8 vf[2][2];
    #pragma unroll
    for (int dh = 0; dh < 2; ++dh)
      #pragma unroll
      for (int hf = 0; hf < 2; ++hf) {
        const int row = dh * 16 + lr;
        const int ch = t * 8 + ((hf * 4 + lg) ^ (lr & 7));
        vf[dh][hf] = *reinterpret_cast<const f16x8*>(&Vlds[row * 1024 + ch * 8]);
      }

    // ---- two 32-key halves; each half interleaves BOTH subtiles ----
    #pragma unroll
    for (int hf = 0; hf < 2; ++hf) {
      // QK^T for both subtiles (4 MFMAs)
      const f32x4 zz = {0.f, 0.f, 0.f, 0.f};
      f32x4 sv[2][2];
      #pragma unroll
      for (int s = 0; s < 2; ++s)
        #pragma unroll
        for (int st = 0; st < 2; ++st)
          sv[s][st] = mfma16h(kf[hf * 2 + st], qf[s], zz);

      // S^T -> LDS for both subtiles (writes bounded by 32 + lg*4 <= 40)
      #pragma unroll
      for (int s = 0; s < 2; ++s)
        #pragma unroll
        for (int st = 0; st < 2; ++st) {
          union { h16x2 h2[2]; ushort4 u; } sw;
          sw.h2[0] = __builtin_amdgcn_cvt_pkrtz(sv[s][st][0], sv[s][st][1]);
          sw.h2[1] = __builtin_amdgcn_cvt_pkrtz(sv[s][st][2], sv[s][st][3]);
          *reinterpret_cast<ushort4*>(&Sbuf[w][s][lr][st * 16 + lg * 4]) = sw.u;
        }

      // read back + exp + PV for both subtiles
      #pragma unroll
      for (int s = 0; s < 2; ++s) {
        const f16x8 sf = *reinterpret_cast<const f16x8*>(&Sbuf[w][s][lr][lg * 8]);
        const f16x8 bfv = *reinterpret_cast<const f16x8*>(&bc[s][hf]);
        const f16x8 sb = sf + bfv;            // v_pk_add_f16
        float e[8];
        #pragma unroll
        for (int i = 0; i < 8; ++i) e[i] = exp2f((float)sb[i]);
        union { h16x2 h2[4]; f16x8 v; } pfu;
        #pragma unroll
        for (int i = 0; i < 4; ++i)
          pfu.h2[i] = __builtin_amdgcn_cvt_pkrtz(e[2 * i], e[2 * i + 1]);
        const f16x8 pf = pfu.v;
        o[s][0] = mfma16h(vf[0][hf], pf, o[s][0]);
        o[s][1] = mfma16h(vf[1][hf], pf, o[s][1]);
        lacc[s] = mfma16h(onesv, pf, lacc[s]);  // l += sum_k p (all rows equal)
      }
    }

    #pragma unroll
    for (int s = 0; s < 2; ++s)
      #pragma unroll
      for (int hf = 0; hf < 2; ++hf)
        bc[s][hf] = bn[s][hf];
  }

  // epilogue: l = lacc[s][0] exactly (B-operand reduction spans all lanes)
  #pragma unroll
  for (int s = 0; s < 2; ++s) {
    const float linv = 1.0f / lacc[s][0];
    ushort4 r0, r1;
    unsigned short* r0p = (unsigned short*)&r0;
    unsigned short* r1p = (unsigned short*)&r1;
    #pragma unroll
    for (int i = 0; i < 4; ++i) {
      r0p[i] = f2h(o[s][0][i] * linv);
      r1p[i] = f2h(o[s][1][i] * linv);
    }
    const int row = (b << 10) + q0w + s * 16 + lr;
    *reinterpret_cast<ushort4*>(&AO[row * 256 + h * 32 + lg * 4]) = r0;
    *reinterpret_cast<ushort4*>(&AO[row * 256 + h * 32 + 16 + lg * 4]) = r1;
  }
}

// ---------------- k4: output projection (W-stationary, f16) --------------------
// grid (64, 4): x = 128-row m-chunk (8 m-tiles), y = col-slab of 64.
__global__ __launch_bounds__(256, 2) void k_oproj(
    const unsigned short* __restrict__ AO, const unsigned short* __restrict__ Wto,
    const float* __restrict__ bo, float* __restrict__ out) {
  const int lane = threadIdx.x & 63;
  const int w = threadIdx.x >> 6;
  const int lr = lane & 15, lg = lane >> 4;
  const int c0 = blockIdx.y * 64 + w * 16;
  const int mbase = blockIdx.x << 7;

  f16x8 bfr[8];
  #pragma unroll
  for (int ks = 0; ks < 8; ++ks)
    bfr[ks] = ldfragh(Wto + (c0 + lr) * 256 + ks * 32 + lg * 8);
  const float bb = bo[c0 + lr];

  for (int mt = 0; mt < 8; ++mt) {
    const int m0 = mbase + mt * 16;
    f16x8 a[8];
    #pragma unroll
    for (int ks = 0; ks < 8; ++ks)
      a[ks] = ldfragh(AO + (m0 + lr) * 256 + ks * 32 + lg * 8);
    f32x4 acc = {0.f, 0.f, 0.f, 0.f};
    #pragma unroll
    for (int ks = 0; ks < 8; ++ks)
      acc = mfma16h(a[ks], bfr[ks], acc);
    #pragma unroll
    for (int i = 0; i < 4; ++i) {
      const int row = m0 + lg * 4 + i;
      out[row * 256 + c0 + lr] = acc[i] + bb;
    }
  }
}

extern "C" void kernel_launch(void* const* d_in, const int* in_sizes, int n_in,
                              void* d_out, int out_size, void* d_ws, size_t ws_size,
                              hipStream_t stream) {
  const float* X   = (const float*)d_in[0];
  const int*   A   = (const int*)d_in[1];
  const float* D   = (const float*)d_in[2];
  const float* Wq  = (const float*)d_in[3];
  const float* bq  = (const float*)d_in[4];
  const float* Wk  = (const float*)d_in[5];
  const float* bk  = (const float*)d_in[6];
  const float* Wv  = (const float*)d_in[7];
  const float* bv  = (const float*)d_in[8];
  const float* Wo  = (const float*)d_in[9];
  const float* bo  = (const float*)d_in[10];
  const float* dsc = (const float*)d_in[11];
  float* out = (float*)d_out;

  unsigned short* ws = (unsigned short*)d_ws;
  unsigned short* Xh   = ws;                   // 2,097,152  (reused as AO later)
  unsigned short* Wt   = ws + 2097152;         //   262,144
  unsigned short* Qb   = ws + 2359296;         // 2,097,152
  unsigned short* Kb   = ws + 4456448;         // 2,097,152
  unsigned short* Vt   = ws + 6553600;         // 2,097,152
  unsigned short* Bias = ws + 8650752;         // 8,388,608  (total ~34.1 MB)
  unsigned short* AO   = Xh;                   // alias: Xh dead after k_qkv_bias

  hipLaunchKernelGGL(k_prep_xw, dim3(3072), dim3(256), 0, stream,
                     X, Wq, Wk, Wv, Wo, Xh, Wt);
  hipLaunchKernelGGL(k_qkv_bias, dim3(8576), dim3(256), 0, stream,
                     Xh, Wt, bq, bk, bv, A, D, dsc, Qb, Kb, Vt, Bias);
  hipLaunchKernelGGL(k_attn, dim3(256), dim3(512), 0, stream,
                     Qb, Kb, Vt, Bias, AO);
  hipLaunchKernelGGL(k_oproj, dim3(64, 4), dim3(256), 0, stream,
                     AO, Wt + 196608, bo, out);
}

// Round 24
// 84.539 us; speedup vs baseline: 8.6961x; 1.0290x over previous
//
#include <hip/hip_runtime.h>

// MultiHeadGraphAttention: B=8, N=1024, IN=OUT=256, H=8, d_k=32
// All-fp16 pipeline, stage-overlapped (best verified configuration, R16):
//   k1: X f32->f16 + W transpose->f16
//   k2: QKV GEMM blocks (0..383) + bias-precompute blocks (384..8575) fused in
//       one launch -> HBM bias stream overlaps compute-bound GEMM on idle CUs
//   k3: fused masked attention (K/V LDS-resident, XOR-swizzled, S^T via LDS,
//       packed-f16 bias add, fixed-max exp2 softmax, l via ones-MFMA)
//   k4: output projection (W-stationary)

typedef _Float16 f16x8 __attribute__((ext_vector_type(8)));
typedef __fp16 h16x2 __attribute__((ext_vector_type(2)));   // cvt_pkrtz result type
typedef float f32x4 __attribute__((ext_vector_type(4)));
typedef int i32x4 __attribute__((ext_vector_type(4)));
typedef unsigned short u16x8 __attribute__((ext_vector_type(8)));

#define DEV static __device__ __forceinline__

#define LOG2E 1.4426950408889634f
#define QSCALE 0.2550351062f   // (1/sqrt(32)) * log2(e)

DEV unsigned short f2h(float f) {    // f32 -> fp16 bits (RNE)
  _Float16 h = (_Float16)f;
  unsigned short u;
  __builtin_memcpy(&u, &h, 2);
  return u;
}

DEV f32x4 mfma16h(f16x8 a, f16x8 b, f32x4 c) {
  return __builtin_amdgcn_mfma_f32_16x16x32_f16(a, b, c, 0, 0, 0);
}

DEV f16x8 ldfragh(const unsigned short* p) {
  return *reinterpret_cast<const f16x8*>(p);
}

// ---------------- k1: X f32 -> f16 ; W -> f16 transposed [n][k] ----------------
// grid 3072: 2048 X-quad blocks + 1024 W blocks.
__global__ __launch_bounds__(256) void k_prep_xw(
    const float* __restrict__ X,
    const float* __restrict__ Wq, const float* __restrict__ Wk,
    const float* __restrict__ Wv, const float* __restrict__ Wo,
    unsigned short* __restrict__ Xh, unsigned short* __restrict__ Wt) {
  const int tid = blockIdx.x * 256 + threadIdx.x;
  const int NX4 = (8192 * 256) / 4;           // 524,288 X quads
  if (tid < NX4) {
    float4 v = reinterpret_cast<const float4*>(X)[tid];
    union { h16x2 h2[2]; ushort4 u; } o;
    o.h2[0] = __builtin_amdgcn_cvt_pkrtz(v.x, v.y);
    o.h2[1] = __builtin_amdgcn_cvt_pkrtz(v.z, v.w);
    reinterpret_cast<ushort4*>(Xh)[tid] = o.u;
  } else {
    int t = tid - NX4;                        // 0 .. 262143
    int mat = t >> 16;
    int e = t & 65535;
    int n = e >> 8, k = e & 255;              // output Wt[mat][n][k]
    const float* W = (mat == 0) ? Wq : (mat == 1) ? Wk : (mat == 2) ? Wv : Wo;
    Wt[t] = f2h(W[k * 256 + n]);
  }
}

// ---------------- k2: QKV GEMM + bias precompute, fused for overlap ------------
// blocks 0..383: W-stationary GEMM (bx&31 = 256-row m-chunk, bx>>5 = mat*4+slab)
// blocks 384..8575: Bias[b][q][k] fp16 = A<=0 ? -60000 : -ds*log2e*D (1 quad/thr)
__global__ __launch_bounds__(256, 2) void k_qkv_bias(
    const unsigned short* __restrict__ Xh, const unsigned short* __restrict__ Wt,
    const float* __restrict__ bq, const float* __restrict__ bk,
    const float* __restrict__ bv,
    const int* __restrict__ A, const float* __restrict__ D,
    const float* __restrict__ dscale,
    unsigned short* __restrict__ Qb, unsigned short* __restrict__ Kb,
    unsigned short* __restrict__ Vt, unsigned short* __restrict__ Bias) {
  if (blockIdx.x >= 384) {
    // ---- bias stream ----
    const int t = (blockIdx.x - 384) * 256 + threadIdx.x;   // quad id, < 2,097,152
    const i32x4 a4 = reinterpret_cast<const i32x4*>(A)[t];
    const f32x4 d4 = reinterpret_cast<const f32x4*>(D)[t];
    const float c = -dscale[0] * LOG2E;
    ushort4 o;
    unsigned short* op = (unsigned short*)&o;
    #pragma unroll
    for (int i = 0; i < 4; ++i)
      op[i] = f2h(a4[i] <= 0 ? -60000.0f : c * d4[i]);
    reinterpret_cast<ushort4*>(Bias)[t] = o;
    return;
  }

  // ---- QKV GEMM (W-stationary) ----
  const int lane = threadIdx.x & 63;
  const int w = threadIdx.x >> 6;
  const int lr = lane & 15, lg = lane >> 4;
  const int yy = blockIdx.x >> 5;             // 0..11 = mat*4 + col-slab
  const int mat = yy >> 2;
  const int nloc = (yy & 3) * 64 + w * 16;
  const int mbase = (blockIdx.x & 31) << 8;

  const unsigned short* Wm = Wt + mat * 65536;
  const float* bias = (mat == 0) ? bq : (mat == 1) ? bk : bv;

  f16x8 bfr[8];
  #pragma unroll
  for (int ks = 0; ks < 8; ++ks)
    bfr[ks] = ldfragh(Wm + (nloc + lr) * 256 + ks * 32 + lg * 8);
  const float bb = bias[nloc + lr];
  const int cm = nloc + lr;
  const int hh = cm >> 5, d = cm & 31;

  for (int mt = 0; mt < 16; ++mt) {
    const int m0 = mbase + mt * 16;
    f16x8 a[8];
    #pragma unroll
    for (int ks = 0; ks < 8; ++ks)
      a[ks] = ldfragh(Xh + (m0 + lr) * 256 + ks * 32 + lg * 8);
    f32x4 acc = {0.f, 0.f, 0.f, 0.f};
    #pragma unroll
    for (int ks = 0; ks < 8; ++ks)
      acc = mfma16h(a[ks], bfr[ks], acc);

    if (mat == 2) {                           // V transposed: 4 consecutive halfs
      union { h16x2 h2[2]; ushort4 u; } vv;
      vv.h2[0] = __builtin_amdgcn_cvt_pkrtz(acc[0] + bb, acc[1] + bb);
      vv.h2[1] = __builtin_amdgcn_cvt_pkrtz(acc[2] + bb, acc[3] + bb);
      const int row = m0 + lg * 4;
      const int bidx = row >> 10, nn = row & 1023;
      *reinterpret_cast<ushort4*>(&Vt[(((bidx * 8 + hh) * 32) + d) * 1024 + nn]) = vv.u;
    } else if (mat == 0) {
      #pragma unroll
      for (int i = 0; i < 4; ++i) {
        const int row = m0 + lg * 4 + i;
        const int bidx = row >> 10, nn = row & 1023;
        Qb[(((bidx * 8 + hh) * 1024) + nn) * 32 + d] = f2h((acc[i] + bb) * QSCALE);
      }
    } else {
      #pragma unroll
      for (int i = 0; i < 4; ++i) {
        const int row = m0 + lg * 4 + i;
        const int bidx = row >> 10, nn = row & 1023;
        Kb[(((bidx * 8 + hh) * 1024) + nn) * 32 + d] = f2h(acc[i] + bb);
      }
    }
  }
}

// ---------------- k3: fused masked attention (all-f16) -------------------------
// grid 256 = (b,h,q-quarter), bi = (h*4+qq)*8 + b  (XCD-affine). 1 block/CU.
// block 512 = 8 waves; wave w owns 32 q-rows (2 subtiles of 16).
// K (64KB) + V^T (64KB) staged in LDS once, XOR-swizzled. Each 64-key tile is
// processed as two 32-key halves; per half, BOTH subtiles' S^T are written to
// disjoint Sbuf regions before either is read. Bias added packed-f16 in
// B-fragment layout; p = exp2(s+bias) (fixed max 0, masked -> exact 0);
// l via ones-MFMA.
__global__ __launch_bounds__(512, 2) void k_attn(
    const unsigned short* __restrict__ Qb, const unsigned short* __restrict__ Kb,
    const unsigned short* __restrict__ Vt, const unsigned short* __restrict__ Bias,
    unsigned short* __restrict__ AO) {
  __shared__ alignas(16) unsigned short Klds[1024 * 32];    // 64KB, seg^=row&3
  __shared__ alignas(16) unsigned short Vlds[32 * 1024];    // 64KB, chunk^=row&7
  __shared__ alignas(16) unsigned short Sbuf[8][2][16][40]; // 20KB: 32 keys + pad

  const int tid = threadIdx.x;
  const int lane = tid & 63;
  const int w = tid >> 6;
  const int lr = lane & 15, lg = lane >> 4;
  const int bi = blockIdx.x;
  const int b = bi & 7;                       // XCD affinity
  const int j = bi >> 3;
  const int h = j >> 2, qq = j & 3;
  const int q0w = qq * 256 + w * 32;

  const unsigned short* Kg = Kb + ((size_t)(b * 8 + h) << 15);
  const unsigned short* Vg = Vt + ((size_t)(b * 8 + h) << 15);
  const unsigned short* Qh = Qb + ((size_t)(b * 8 + h) << 15);

  // ---- stage K: linear global 16B/thread -> swizzled LDS ----
  #pragma unroll
  for (int p = 0; p < 8; ++p) {
    const int c = tid + p * 512;              // 16B chunk id, 4096 total
    const int row = c >> 2, seg = c & 3;
    const u16x8 v = *reinterpret_cast<const u16x8*>(Kg + c * 8);
    *reinterpret_cast<u16x8*>(&Klds[row * 32 + ((seg ^ (row & 3)) << 3)]) = v;
  }
  // ---- stage V^T: linear global -> swizzled LDS ----
  #pragma unroll
  for (int p = 0; p < 8; ++p) {
    const int c = tid + p * 512;              // 16B chunk id, 4096 total
    const int row = c >> 7, ch = c & 127;
    const u16x8 v = *reinterpret_cast<const u16x8*>(Vg + c * 8);
    *reinterpret_cast<u16x8*>(&Vlds[row * 1024 + ((ch ^ (row & 7)) << 3)]) = v;
  }

  // Q fragments for the wave's 2 subtiles, bias base pointers
  f16x8 qf[2];
  qf[0] = ldfragh(Qh + (q0w + lr) * 32 + lg * 8);
  qf[1] = ldfragh(Qh + (q0w + 16 + lr) * 32 + lg * 8);
  const unsigned short* Br0 = Bias + ((size_t)b << 20) + (size_t)(q0w + lr) * 1024;
  const unsigned short* Br1 = Br0 + (size_t)16 * 1024;

  // bias prefetch for tile 0: [sub][half], half = 32 keys
  u16x8 bc[2][2], bn[2][2];
  #pragma unroll
  for (int hf = 0; hf < 2; ++hf) {
    bc[0][hf] = *reinterpret_cast<const u16x8*>(Br0 + hf * 32 + lg * 8);
    bc[1][hf] = *reinterpret_cast<const u16x8*>(Br1 + hf * 32 + lg * 8);
  }

  __syncthreads();

  f32x4 o[2][2];                              // [sub][dh]
  f32x4 lacc[2];                              // [sub] l accumulator (ones-MFMA)
  #pragma unroll
  for (int s = 0; s < 2; ++s) {
    #pragma unroll
    for (int dh = 0; dh < 2; ++dh) o[s][dh] = f32x4{0.f, 0.f, 0.f, 0.f};
    lacc[s] = f32x4{0.f, 0.f, 0.f, 0.f};
  }
  f16x8 onesv;
  #pragma unroll
  for (int i = 0; i < 8; ++i) onesv[i] = (_Float16)1.0f;

  for (int t = 0; t < 16; ++t) {
    const int k0 = t << 6;
    if (t < 15) {                             // bias(t+1) prefetch (HBM stream)
      #pragma unroll
      for (int hf = 0; hf < 2; ++hf) {
        bn[0][hf] = *reinterpret_cast<const u16x8*>(Br0 + k0 + 64 + hf * 32 + lg * 8);
        bn[1][hf] = *reinterpret_cast<const u16x8*>(Br1 + k0 + 64 + hf * 32 + lg * 8);
      }
    }

    // K fragments from LDS (seg XOR swizzle)
    f16x8 kf[4];
    #pragma unroll
    for (int st = 0; st < 4; ++st) {
      const int row = k0 + st * 16 + lr;
      kf[st] = *reinterpret_cast<const f16x8*>(
          &Klds[row * 32 + ((lg ^ (lr & 3)) << 3)]);
    }
    // V^T fragments from LDS (chunk XOR swizzle); shared by both subtiles
    f16x8 vf[2][2];
    #pragma unroll
    for (int dh = 0; dh < 2; ++dh)
      #pragma unroll
      for (int hf = 0; hf < 2; ++hf) {
        const int row = dh * 16 + lr;
        const int ch = t * 8 + ((hf * 4 + lg) ^ (lr & 7));
        vf[dh][hf] = *reinterpret_cast<const f16x8*>(&Vlds[row * 1024 + ch * 8]);
      }

    // ---- two 32-key halves; each half interleaves BOTH subtiles ----
    #pragma unroll
    for (int hf = 0; hf < 2; ++hf) {
      // QK^T for both subtiles (4 MFMAs)
      const f32x4 zz = {0.f, 0.f, 0.f, 0.f};
      f32x4 sv[2][2];
      #pragma unroll
      for (int s = 0; s < 2; ++s)
        #pragma unroll
        for (int st = 0; st < 2; ++st)
          sv[s][st] = mfma16h(kf[hf * 2 + st], qf[s], zz);

      // S^T -> LDS for both subtiles (writes bounded by 32 + lg*4 <= 40)
      #pragma unroll
      for (int s = 0; s < 2; ++s)
        #pragma unroll
        for (int st = 0; st < 2; ++st) {
          union { h16x2 h2[2]; ushort4 u; } sw;
          sw.h2[0] = __builtin_amdgcn_cvt_pkrtz(sv[s][st][0], sv[s][st][1]);
          sw.h2[1] = __builtin_amdgcn_cvt_pkrtz(sv[s][st][2], sv[s][st][3]);
          *reinterpret_cast<ushort4*>(&Sbuf[w][s][lr][st * 16 + lg * 4]) = sw.u;
        }

      // read back + exp + PV for both subtiles
      #pragma unroll
      for (int s = 0; s < 2; ++s) {
        const f16x8 sf = *reinterpret_cast<const f16x8*>(&Sbuf[w][s][lr][lg * 8]);
        const f16x8 bfv = *reinterpret_cast<const f16x8*>(&bc[s][hf]);
        const f16x8 sb = sf + bfv;            // v_pk_add_f16
        float e[8];
        #pragma unroll
        for (int i = 0; i < 8; ++i) e[i] = exp2f((float)sb[i]);
        union { h16x2 h2[4]; f16x8 v; } pfu;
        #pragma unroll
        for (int i = 0; i < 4; ++i)
          pfu.h2[i] = __builtin_amdgcn_cvt_pkrtz(e[2 * i], e[2 * i + 1]);
        const f16x8 pf = pfu.v;
        o[s][0] = mfma16h(vf[0][hf], pf, o[s][0]);
        o[s][1] = mfma16h(vf[1][hf], pf, o[s][1]);
        lacc[s] = mfma16h(onesv, pf, lacc[s]);  // l += sum_k p (all rows equal)
      }
    }

    #pragma unroll
    for (int s = 0; s < 2; ++s)
      #pragma unroll
      for (int hf = 0; hf < 2; ++hf)
        bc[s][hf] = bn[s][hf];
  }

  // epilogue: l = lacc[s][0] exactly (B-operand reduction spans all lanes)
  #pragma unroll
  for (int s = 0; s < 2; ++s) {
    const float linv = 1.0f / lacc[s][0];
    ushort4 r0, r1;
    unsigned short* r0p = (unsigned short*)&r0;
    unsigned short* r1p = (unsigned short*)&r1;
    #pragma unroll
    for (int i = 0; i < 4; ++i) {
      r0p[i] = f2h(o[s][0][i] * linv);
      r1p[i] = f2h(o[s][1][i] * linv);
    }
    const int row = (b << 10) + q0w + s * 16 + lr;
    *reinterpret_cast<ushort4*>(&AO[row * 256 + h * 32 + lg * 4]) = r0;
    *reinterpret_cast<ushort4*>(&AO[row * 256 + h * 32 + 16 + lg * 4]) = r1;
  }
}

// ---------------- k4: output projection (W-stationary, f16) --------------------
// grid (64, 4): x = 128-row m-chunk (8 m-tiles), y = col-slab of 64.
__global__ __launch_bounds__(256, 2) void k_oproj(
    const unsigned short* __restrict__ AO, const unsigned short* __restrict__ Wto,
    const float* __restrict__ bo, float* __restrict__ out) {
  const int lane = threadIdx.x & 63;
  const int w = threadIdx.x >> 6;
  const int lr = lane & 15, lg = lane >> 4;
  const int c0 = blockIdx.y * 64 + w * 16;
  const int mbase = blockIdx.x << 7;

  f16x8 bfr[8];
  #pragma unroll
  for (int ks = 0; ks < 8; ++ks)
    bfr[ks] = ldfragh(Wto + (c0 + lr) * 256 + ks * 32 + lg * 8);
  const float bb = bo[c0 + lr];

  for (int mt = 0; mt < 8; ++mt) {
    const int m0 = mbase + mt * 16;
    f16x8 a[8];
    #pragma unroll
    for (int ks = 0; ks < 8; ++ks)
      a[ks] = ldfragh(AO + (m0 + lr) * 256 + ks * 32 + lg * 8);
    f32x4 acc = {0.f, 0.f, 0.f, 0.f};
    #pragma unroll
    for (int ks = 0; ks < 8; ++ks)
      acc = mfma16h(a[ks], bfr[ks], acc);
    #pragma unroll
    for (int i = 0; i < 4; ++i) {
      const int row = m0 + lg * 4 + i;
      out[row * 256 + c0 + lr] = acc[i] + bb;
    }
  }
}

extern "C" void kernel_launch(void* const* d_in, const int* in_sizes, int n_in,
                              void* d_out, int out_size, void* d_ws, size_t ws_size,
                              hipStream_t stream) {
  const float* X   = (const float*)d_in[0];
  const int*   A   = (const int*)d_in[1];
  const float* D   = (const float*)d_in[2];
  const float* Wq  = (const float*)d_in[3];
  const float* bq  = (const float*)d_in[4];
  const float* Wk  = (const float*)d_in[5];
  const float* bk  = (const float*)d_in[6];
  const float* Wv  = (const float*)d_in[7];
  const float* bv  = (const float*)d_in[8];
  const float* Wo  = (const float*)d_in[9];
  const float* bo  = (const float*)d_in[10];
  const float* dsc = (const float*)d_in[11];
  float* out = (float*)d_out;

  unsigned short* ws = (unsigned short*)d_ws;
  unsigned short* Xh   = ws;                   // 2,097,152  (reused as AO later)
  unsigned short* Wt   = ws + 2097152;         //   262,144
  unsigned short* Qb   = ws + 2359296;         // 2,097,152
  unsigned short* Kb   = ws + 4456448;         // 2,097,152
  unsigned short* Vt   = ws + 6553600;         // 2,097,152
  unsigned short* Bias = ws + 8650752;         // 8,388,608  (total ~34.1 MB)
  unsigned short* AO   = Xh;                   // alias: Xh dead after k_qkv_bias

  hipLaunchKernelGGL(k_prep_xw, dim3(3072), dim3(256), 0, stream,
                     X, Wq, Wk, Wv, Wo, Xh, Wt);
  hipLaunchKernelGGL(k_qkv_bias, dim3(8576), dim3(256), 0, stream,
                     Xh, Wt, bq, bk, bv, A, D, dsc, Qb, Kb, Vt, Bias);
  hipLaunchKernelGGL(k_attn, dim3(256), dim3(512), 0, stream,
                     Qb, Kb, Vt, Bias, AO);
  hipLaunchKernelGGL(k_oproj, dim3(64, 4), dim3(256), 0, stream,
                     AO, Wt + 196608, bo, out);
}